// Round 4
// baseline (268.807 us; speedup 1.0000x reference)
//
#include <hip/hip_runtime.h>
#include <math.h>

// Problem constants (match reference)
#define B_N 8
#define A_N 49104
#define M_N 50
#define K_N 80
#define BETA_C (1.0f / 9.0f)

#define APB   192               // anchors per block
#define NBLK  256               // ceil(A_N/APB); 256*192 = 49152 >= 49104
#define F4PA  20                // float4 per anchor (K=80 / 4)
#define ITER2 15                // phase-2 iterations: APB*F4PA / 256
#define PF    5                 // prefetched iterations (overlap phase-1 VALU)
#define NBLOCKS_TOTAL (NBLK * B_N)   // 2048

#define C_NEG 0.51986039f       // 0.75 * ln(2): neg focal in log2 form
#define C_POS 0.17328680f       // 0.25 * ln(2): pos focal in log2 form

typedef float vf4 __attribute__((ext_vector_type(4)));

__device__ __forceinline__ float wred(float v) {
#pragma unroll
    for (int off = 32; off > 0; off >>= 1) v += __shfl_down(v, off, 64);
    return v;
}

// Fused single-kernel design.
// Phase 1: per-anchor assignment + smooth-L1 over the VALID-PREFIX of boxes
//   (ref pads at the end; nv via per-wave ballot; invalid boxes score -1.0 in
//   ref so first-argmax over the prefix is identical; nv==0 -> background).
// Phase 2: focal loss ALL-AS-NEGATIVE (0.75*p^2*(-ln(1-p)), mask folded into
//   one fma weight) + rare positive-class correction. First PF float4s are
//   issued before phase 1 so HBM streams under phase-1 VALU.
// Finalize: folded in via last-block reduce (release: threadfence+atomicAdd;
//   acquire: threadfence after observing last). Reduction order is identical
//   to the old finalize_kernel -> bit-exact output. Counter is memset to 0
//   on-stream each launch by kernel_launch.
// grid = (NBLK, B_N), block = 256
__global__ __launch_bounds__(256, 6) void fused_kernel(
    const float* __restrict__ logits,    // (B, A*K)
    const float* __restrict__ reg,       // (B,A,4)
    const float* __restrict__ anchors,   // (A,4)
    const float* __restrict__ boxes,     // (B,M,4), -1 padded (suffix)
    const int* __restrict__ classes,     // (B,M)
    float* __restrict__ clspart,         // (B,NBLK)
    float* __restrict__ regpart,         // (B,NBLK)
    float* __restrict__ npospart,        // (B,NBLK)
    unsigned int* __restrict__ counter,  // arrival counter (zeroed per launch)
    float* __restrict__ out)             // (3,)
{
    const int b   = blockIdx.y;
    const int a0  = blockIdx.x * APB;
    const int tid = threadIdx.x;
    const int a   = a0 + tid;

    __shared__ float4 sb4[M_N];
    __shared__ float  sarea[M_N];
    __shared__ int    sc[M_N];
    __shared__ int    sstat[APB];

    // ---- tiny staging (barrier here drains ONLY these small loads) ----
    if (tid < M_N) {
        const float4 bb = ((const float4*)boxes)[b * M_N + tid];
        sb4[tid]   = bb;
        sarea[tid] = (bb.z - bb.x) * (bb.w - bb.y);
        sc[tid]    = classes[b * M_N + tid];
    }
    const float4 an = ((const float4*)anchors)[min(a, A_N - 1)];
    __syncthreads();

    // ---- prefetch first PF logit float4s: streams during phase-1 VALU ----
    const vf4* img4 = (const vf4*)(logits + (size_t)b * ((size_t)A_N * K_N));
    vf4 pf[PF];
#pragma unroll
    for (int it = 0; it < PF; ++it) {
        const int li = it * 256 + tid;
        const int la = li / F4PA;
        const int fc = li - la * F4PA;
        const int ga = min(a0 + la, A_N - 1);
        pf[it] = __builtin_nontemporal_load(img4 + ((size_t)ga * F4PA + fc));
    }

    // ---- valid-prefix length, computed redundantly per wave (no barrier) ----
    const int lane64 = tid & 63;
    const bool vlane = (lane64 < M_N) && (sb4[lane64].x != -1.0f);
    const unsigned long long vmask = __ballot(vlane);
    const int nv = (int)__builtin_ctzll(~vmask | (1ull << M_N)); // first invalid

    // ---------------- phase 1: assignment + smooth-L1 ----------------
    float regl = 0.0f;
    float posf = 0.0f;
    if (tid < APB) {
        int s = -1;                      // out-of-range / ignored anchors
        if (a < A_N) {
            const float aw = an.z - an.x;
            const float ah = an.w - an.y;
            const float areaA = aw * ah;

            float best = -2.0f;
            int bi = 0;
#pragma unroll 2
            for (int m = 0; m < nv; ++m) {
                const float4 bb = sb4[m];
                const float iw = fmaxf(fminf(an.z, bb.z) - fmaxf(an.x, bb.x), 0.0f);
                const float ih = fmaxf(fminf(an.w, bb.w) - fmaxf(an.y, bb.y), 0.0f);
                const float inter = iw * ih;
                const float ua = fmaxf(areaA + sarea[m] - inter, 1e-8f);
                const float val = inter / ua;   // IEEE divide: matches ref argmax
                if (val > best) { best = val; bi = m; }  // strict > == first argmax
            }

            if (best >= 0.5f) {
                s = sc[bi];
                posf = 1.0f;
                const float4 r = ((const float4*)reg)[b * A_N + a];
                const float4 g = sb4[bi];
                const float acx = an.x + 0.5f * aw;
                const float acy = an.y + 0.5f * ah;
                const float gw0 = g.z - g.x;
                const float gh0 = g.w - g.y;
                const float gcx = g.x + 0.5f * gw0;
                const float gcy = g.y + 0.5f * gh0;
                const float gw = fmaxf(gw0, 1.0f);
                const float gh = fmaxf(gh0, 1.0f);
                const float t0 = ((gcx - acx) / aw) / 0.1f;
                const float t1 = ((gcy - acy) / ah) / 0.1f;
                const float t2 = logf(gw / aw) / 0.2f;
                const float t3 = logf(gh / ah) / 0.2f;
                float d, sl;
                d = fabsf(t0 - r.x); sl  = (d <= BETA_C) ? 0.5f * d * d / BETA_C : d - 0.5f * BETA_C;
                d = fabsf(t1 - r.y); sl += (d <= BETA_C) ? 0.5f * d * d / BETA_C : d - 0.5f * BETA_C;
                d = fabsf(t2 - r.z); sl += (d <= BETA_C) ? 0.5f * d * d / BETA_C : d - 0.5f * BETA_C;
                d = fabsf(t3 - r.w); sl += (d <= BETA_C) ? 0.5f * d * d / BETA_C : d - 0.5f * BETA_C;
                regl = sl;
            } else if (best < 0.4f) {
                s = 0;
            }
        }
        sstat[tid] = s;
    }
    __syncthreads();   // drains pf loads too -- they landed during phase 1

    // -------- phase 2: all-as-negative focal + rare positive fixup --------
    float cls = 0.0f;
#define PROC(P4)                                                               \
    {                                                                          \
        const int st = sstat[la];       /* -1 ignore, 0 neg, 1..80 pos */      \
        const float wgt = (st < 0) ? 0.0f : -C_NEG;                            \
        _Pragma("unroll")                                                      \
        for (int j = 0; j < 4; ++j) {                                          \
            const float p  = fminf(fmaxf((P4)[j], 1e-4f), 1.0f - 1e-4f);       \
            const float om = 1.0f - p;                                         \
            const float t  = (p * p) * __log2f(om);   /* t < 0 */              \
            cls = fmaf(wgt, t, cls);                                           \
        }                                                                      \
        if (st >= 1) {                  /* positive anchor (rare) */           \
            const unsigned jo = (unsigned)(st - 1 - 4 * fc);                   \
            if (jo < 4u) {              /* its class lives in this float4 */   \
                const float pj = (jo == 0) ? (P4)[0] : (jo == 1) ? (P4)[1]     \
                               : (jo == 2) ? (P4)[2] : (P4)[3];                \
                const float pc = fminf(fmaxf(pj, 1e-4f), 1.0f - 1e-4f);        \
                const float om = 1.0f - pc;                                    \
                const float t  = (pc * pc) * __log2f(om);                      \
                cls = fmaf(C_NEG, t, cls);                 /* undo neg term */ \
                cls = fmaf((C_POS * om) * om, -__log2f(pc), cls); /* pos */    \
            }                                                                  \
        }                                                                      \
    }

#pragma unroll
    for (int it = 0; it < PF; ++it) {
        const int li = it * 256 + tid;
        const int la = li / F4PA;
        const int fc = li - la * F4PA;
        PROC(pf[it]);
    }
#pragma unroll 5
    for (int it = PF; it < ITER2; ++it) {
        const int li = it * 256 + tid;
        const int la = li / F4PA;
        const int fc = li - la * F4PA;
        const int ga = min(a0 + la, A_N - 1);
        const vf4 p4 = __builtin_nontemporal_load(img4 + ((size_t)ga * F4PA + fc));
        PROC(p4);
    }
#undef PROC

    // ---------------- block reduction + partial write ----------------
    const float cw = wred(cls);
    const float rw = wred(regl);
    const float pw = wred(posf);
    __shared__ float sred[12];
    __shared__ unsigned int slast;
    const int lane = tid & 63, wid = tid >> 6;
    if (lane == 0) { sred[wid] = cw; sred[4 + wid] = rw; sred[8 + wid] = pw; }
    __syncthreads();
    if (tid == 0) {
        clspart[b * NBLK + blockIdx.x]  = sred[0] + sred[1] + sred[2] + sred[3];
        regpart[b * NBLK + blockIdx.x]  = sred[4] + sred[5] + sred[6] + sred[7];
        npospart[b * NBLK + blockIdx.x] = sred[8] + sred[9] + sred[10] + sred[11];
        __threadfence();                              // release partials
        const unsigned int old = atomicAdd(counter, 1u);
        slast = (old == (unsigned int)(NBLOCKS_TOTAL - 1)) ? 1u : 0u;
    }
    __syncthreads();
    if (slast == 0u) return;

    // ---------------- last block: finalize (bit-exact vs old kernel) ------
    __threadfence();                                  // acquire partials
    {
        const int bb = tid >> 5;         // batch 0..7
        const int l5 = tid & 31;         // lane within batch group
        float cs = 0.0f, rs = 0.0f, np = 0.0f;
#pragma unroll
        for (int i = 0; i < NBLK / 32; ++i) {
            const int idx = bb * NBLK + l5 + i * 32;
            cs += clspart[idx];
            rs += regpart[idx];
            np += npospart[idx];
        }
#pragma unroll
        for (int off = 16; off > 0; off >>= 1) {      // reduce 32-lane group
            cs += __shfl_down(cs, off, 32);
            rs += __shfl_down(rs, off, 32);
            np += __shfl_down(np, off, 32);
        }
        __shared__ float scs[B_N], srs[B_N], snp[B_N];
        if (l5 == 0) { scs[bb] = cs; srs[bb] = rs; snp[bb] = np; }
        __syncthreads();
        if (tid == 0) {
            float clsAcc = 0.0f, regAcc = 0.0f;
#pragma unroll
            for (int i = 0; i < B_N; ++i) {
                const float fnp = fmaxf(snp[i], 1.0f);
                clsAcc += scs[i] / fnp;
                regAcc += srs[i] / (4.0f * fnp);
            }
            const float cl = clsAcc / (float)B_N;
            const float rl = regAcc / (float)B_N;
            out[0] = cl;
            out[1] = rl;
            out[2] = cl + rl;
        }
    }
}

extern "C" void kernel_launch(void* const* d_in, const int* in_sizes, int n_in,
                              void* d_out, int out_size, void* d_ws, size_t ws_size,
                              hipStream_t stream) {
    const float* cls_logits = (const float*)d_in[0];  // (B,A,K)
    const float* reg_preds  = (const float*)d_in[1];  // (B,A,4)
    const float* anchors    = (const float*)d_in[2];  // (A,4)
    const float* boxes      = (const float*)d_in[3];  // (B,M,4)
    const int*   classes    = (const int*)d_in[4];    // (B,M)
    float* out = (float*)d_out;

    char* ws = (char*)d_ws;
    float* clspart  = (float*)ws; ws += (size_t)B_N * NBLK * sizeof(float);  // 8 KB
    float* regpart  = (float*)ws; ws += (size_t)B_N * NBLK * sizeof(float);  // 8 KB
    float* npospart = (float*)ws; ws += (size_t)B_N * NBLK * sizeof(float);  // 8 KB
    unsigned int* counter = (unsigned int*)ws;

    // Zero the arrival counter on-stream (graph-capture-safe; ~free dispatch,
    // replaces the old finalize_kernel dispatch).
    hipMemsetAsync(counter, 0, sizeof(unsigned int), stream);

    dim3 g1(NBLK, B_N);
    fused_kernel<<<g1, 256, 0, stream>>>(cls_logits, reg_preds, anchors, boxes,
                                         classes, clspart, regpart, npospart,
                                         counter, out);
}

// Round 5
// 182.710 us; speedup vs baseline: 1.4712x; 1.4712x over previous
//
#include <hip/hip_runtime.h>
#include <math.h>

// Problem constants (match reference)
#define B_N 8
#define A_N 49104
#define M_N 50
#define K_N 80
#define BETA_C (1.0f / 9.0f)

#define APB   192               // anchors per block
#define NBLK  256               // ceil(A_N/APB); 256*192 = 49152 >= 49104
#define F4PA  20                // float4 per anchor (K=80 / 4)
#define ITER2 15                // phase-2 iterations: APB*F4PA / 256
#define PF    5                 // prefetched iterations (overlap phase-1 VALU)

#define C_NEG 0.51986039f       // 0.75 * ln(2): neg focal in log2 form
#define C_POS 0.17328680f       // 0.25 * ln(2): pos focal in log2 form

typedef float vf4 __attribute__((ext_vector_type(4)));

__device__ __forceinline__ float wred(float v) {
#pragma unroll
    for (int off = 32; off > 0; off >>= 1) v += __shfl_down(v, off, 64);
    return v;
}

// Fused kernel (two-kernel structure is deliberate: a last-block-reduce
// variant with per-block device-scope __threadfence caused chip-wide L2
// writeback/invalidate on gfx950's non-coherent XCD L2s -> 5x slowdown.
// R4 lesson: keep the tiny finalize dispatch.)
// Phase 1 = per-anchor assignment + smooth-L1 (192 anchors/blk) over the
// VALID-PREFIX of boxes (ref pads at the end; nv via per-wave ballot;
// invalid boxes score -1.0 in ref so first-argmax over the prefix is
// identical; nv==0 -> best=-2 -> background, matching ref).
// Phase 2 = focal loss ALL-AS-NEGATIVE (0.75*p^2*(-ln(1-p)), mask folded
// into one fma weight) + rare positive-class correction branch.
// First PF logit float4s issued BEFORE phase 1 so HBM streams under the
// phase-1 VALU.
// grid = (NBLK, B_N), block = 256
__global__ __launch_bounds__(256, 6) void fused_kernel(
    const float* __restrict__ logits,    // (B, A*K)
    const float* __restrict__ reg,       // (B,A,4)
    const float* __restrict__ anchors,   // (A,4)
    const float* __restrict__ boxes,     // (B,M,4), -1 padded (suffix)
    const int* __restrict__ classes,     // (B,M)
    float* __restrict__ clspart,         // (B,NBLK)
    float* __restrict__ regpart,         // (B,NBLK)
    float* __restrict__ npospart)        // (B,NBLK)
{
    const int b   = blockIdx.y;
    const int a0  = blockIdx.x * APB;
    const int tid = threadIdx.x;
    const int a   = a0 + tid;

    __shared__ float4 sb4[M_N];
    __shared__ float  sarea[M_N];
    __shared__ int    sc[M_N];
    __shared__ int    sstat[APB];

    // ---- tiny staging (barrier here drains ONLY these small loads) ----
    if (tid < M_N) {
        const float4 bb = ((const float4*)boxes)[b * M_N + tid];
        sb4[tid]   = bb;
        sarea[tid] = (bb.z - bb.x) * (bb.w - bb.y);
        sc[tid]    = classes[b * M_N + tid];
    }
    const float4 an = ((const float4*)anchors)[min(a, A_N - 1)];
    __syncthreads();

    // ---- prefetch first PF logit float4s: streams during phase-1 VALU ----
    const vf4* img4 = (const vf4*)(logits + (size_t)b * ((size_t)A_N * K_N));
    vf4 pf[PF];
#pragma unroll
    for (int it = 0; it < PF; ++it) {
        const int li = it * 256 + tid;
        const int la = li / F4PA;
        const int fc = li - la * F4PA;
        const int ga = min(a0 + la, A_N - 1);
        pf[it] = __builtin_nontemporal_load(img4 + ((size_t)ga * F4PA + fc));
    }

    // ---- valid-prefix length, computed redundantly per wave (no barrier) ----
    const int lane64 = tid & 63;
    const bool vlane = (lane64 < M_N) && (sb4[lane64].x != -1.0f);
    const unsigned long long vmask = __ballot(vlane);
    const int nv = (int)__builtin_ctzll(~vmask | (1ull << M_N)); // first invalid

    // ---------------- phase 1: assignment + smooth-L1 ----------------
    float regl = 0.0f;
    float posf = 0.0f;
    if (tid < APB) {
        int s = -1;                      // out-of-range / ignored anchors
        if (a < A_N) {
            const float aw = an.z - an.x;
            const float ah = an.w - an.y;
            const float areaA = aw * ah;

            float best = -2.0f;
            int bi = 0;
#pragma unroll 2
            for (int m = 0; m < nv; ++m) {
                const float4 bb = sb4[m];
                const float iw = fmaxf(fminf(an.z, bb.z) - fmaxf(an.x, bb.x), 0.0f);
                const float ih = fmaxf(fminf(an.w, bb.w) - fmaxf(an.y, bb.y), 0.0f);
                const float inter = iw * ih;
                const float ua = fmaxf(areaA + sarea[m] - inter, 1e-8f);
                const float val = inter / ua;   // IEEE divide: matches ref argmax
                if (val > best) { best = val; bi = m; }  // strict > == first argmax
            }

            if (best >= 0.5f) {
                s = sc[bi];
                posf = 1.0f;
                const float4 r = ((const float4*)reg)[b * A_N + a];
                const float4 g = sb4[bi];
                const float acx = an.x + 0.5f * aw;
                const float acy = an.y + 0.5f * ah;
                const float gw0 = g.z - g.x;
                const float gh0 = g.w - g.y;
                const float gcx = g.x + 0.5f * gw0;
                const float gcy = g.y + 0.5f * gh0;
                const float gw = fmaxf(gw0, 1.0f);
                const float gh = fmaxf(gh0, 1.0f);
                const float t0 = ((gcx - acx) / aw) / 0.1f;
                const float t1 = ((gcy - acy) / ah) / 0.1f;
                const float t2 = logf(gw / aw) / 0.2f;
                const float t3 = logf(gh / ah) / 0.2f;
                float d, sl;
                d = fabsf(t0 - r.x); sl  = (d <= BETA_C) ? 0.5f * d * d / BETA_C : d - 0.5f * BETA_C;
                d = fabsf(t1 - r.y); sl += (d <= BETA_C) ? 0.5f * d * d / BETA_C : d - 0.5f * BETA_C;
                d = fabsf(t2 - r.z); sl += (d <= BETA_C) ? 0.5f * d * d / BETA_C : d - 0.5f * BETA_C;
                d = fabsf(t3 - r.w); sl += (d <= BETA_C) ? 0.5f * d * d / BETA_C : d - 0.5f * BETA_C;
                regl = sl;
            } else if (best < 0.4f) {
                s = 0;
            }
        }
        sstat[tid] = s;
    }
    __syncthreads();   // drains pf loads too -- they landed during phase 1

    // -------- phase 2: all-as-negative focal + rare positive fixup --------
    float cls = 0.0f;
#define PROC(P4)                                                               \
    {                                                                          \
        const int st = sstat[la];       /* -1 ignore, 0 neg, 1..80 pos */      \
        const float wgt = (st < 0) ? 0.0f : -C_NEG;                            \
        _Pragma("unroll")                                                      \
        for (int j = 0; j < 4; ++j) {                                          \
            const float p  = fminf(fmaxf((P4)[j], 1e-4f), 1.0f - 1e-4f);       \
            const float om = 1.0f - p;                                         \
            const float t  = (p * p) * __log2f(om);   /* t < 0 */              \
            cls = fmaf(wgt, t, cls);                                           \
        }                                                                      \
        if (st >= 1) {                  /* positive anchor (rare) */           \
            const unsigned jo = (unsigned)(st - 1 - 4 * fc);                   \
            if (jo < 4u) {              /* its class lives in this float4 */   \
                const float pj = (jo == 0) ? (P4)[0] : (jo == 1) ? (P4)[1]     \
                               : (jo == 2) ? (P4)[2] : (P4)[3];                \
                const float pc = fminf(fmaxf(pj, 1e-4f), 1.0f - 1e-4f);        \
                const float om = 1.0f - pc;                                    \
                const float t  = (pc * pc) * __log2f(om);                      \
                cls = fmaf(C_NEG, t, cls);                 /* undo neg term */ \
                cls = fmaf((C_POS * om) * om, -__log2f(pc), cls); /* pos */    \
            }                                                                  \
        }                                                                      \
    }

#pragma unroll
    for (int it = 0; it < PF; ++it) {
        const int li = it * 256 + tid;
        const int la = li / F4PA;
        const int fc = li - la * F4PA;
        PROC(pf[it]);
    }
#pragma unroll 5
    for (int it = PF; it < ITER2; ++it) {
        const int li = it * 256 + tid;
        const int la = li / F4PA;
        const int fc = li - la * F4PA;
        const int ga = min(a0 + la, A_N - 1);
        const vf4 p4 = __builtin_nontemporal_load(img4 + ((size_t)ga * F4PA + fc));
        PROC(p4);
    }
#undef PROC

    // ---------------- block reduction ----------------
    const float cw = wred(cls);
    const float rw = wred(regl);
    const float pw = wred(posf);
    __shared__ float sred[12];
    const int lane = tid & 63, wid = tid >> 6;
    if (lane == 0) { sred[wid] = cw; sred[4 + wid] = rw; sred[8 + wid] = pw; }
    __syncthreads();
    if (tid == 0) {
        clspart[b * NBLK + blockIdx.x]  = sred[0] + sred[1] + sred[2] + sred[3];
        regpart[b * NBLK + blockIdx.x]  = sred[4] + sred[5] + sred[6] + sred[7];
        npospart[b * NBLK + blockIdx.x] = sred[8] + sred[9] + sred[10] + sred[11];
    }
}

// Final reduction + normalization. 1 block, 256 threads = 8 batches x 32
// lanes in ONE pass. Deterministic.
__global__ __launch_bounds__(256) void finalize_kernel(
    const float* __restrict__ clspart,
    const float* __restrict__ regpart,
    const float* __restrict__ npospart,
    float* __restrict__ out)
{
    const int tid = threadIdx.x;
    const int bb  = tid >> 5;            // batch 0..7
    const int l5  = tid & 31;            // lane within batch group
    float cs = 0.0f, rs = 0.0f, np = 0.0f;
#pragma unroll
    for (int i = 0; i < NBLK / 32; ++i) {
        const int idx = bb * NBLK + l5 + i * 32;
        cs += clspart[idx];
        rs += regpart[idx];
        np += npospart[idx];
    }
#pragma unroll
    for (int off = 16; off > 0; off >>= 1) {  // reduce within 32-lane group
        cs += __shfl_down(cs, off, 32);
        rs += __shfl_down(rs, off, 32);
        np += __shfl_down(np, off, 32);
    }
    __shared__ float scs[B_N], srs[B_N], snp[B_N];
    if (l5 == 0) { scs[bb] = cs; srs[bb] = rs; snp[bb] = np; }
    __syncthreads();
    if (tid == 0) {
        float clsAcc = 0.0f, regAcc = 0.0f;
#pragma unroll
        for (int i = 0; i < B_N; ++i) {
            const float fnp = fmaxf(snp[i], 1.0f);
            clsAcc += scs[i] / fnp;
            regAcc += srs[i] / (4.0f * fnp);
        }
        const float cl = clsAcc / (float)B_N;
        const float rl = regAcc / (float)B_N;
        out[0] = cl;
        out[1] = rl;
        out[2] = cl + rl;
    }
}

extern "C" void kernel_launch(void* const* d_in, const int* in_sizes, int n_in,
                              void* d_out, int out_size, void* d_ws, size_t ws_size,
                              hipStream_t stream) {
    const float* cls_logits = (const float*)d_in[0];  // (B,A,K)
    const float* reg_preds  = (const float*)d_in[1];  // (B,A,4)
    const float* anchors    = (const float*)d_in[2];  // (A,4)
    const float* boxes      = (const float*)d_in[3];  // (B,M,4)
    const int*   classes    = (const int*)d_in[4];    // (B,M)
    float* out = (float*)d_out;

    char* ws = (char*)d_ws;
    float* clspart  = (float*)ws; ws += (size_t)B_N * NBLK * sizeof(float);  // 8 KB
    float* regpart  = (float*)ws; ws += (size_t)B_N * NBLK * sizeof(float);  // 8 KB
    float* npospart = (float*)ws;                                            // 8 KB

    dim3 g1(NBLK, B_N);
    fused_kernel<<<g1, 256, 0, stream>>>(cls_logits, reg_preds, anchors, boxes,
                                         classes, clspart, regpart, npospart);
    finalize_kernel<<<1, 256, 0, stream>>>(clspart, regpart, npospart, out);
}